// Round 8
// baseline (22.508 us; speedup 1.0000x reference)
//
#include <hip/hip_runtime.h>

// SegBrightnessLoss reduced to per-class {S_i, C_i} + global SS:
//   d2_i = S_i/N,  d3_i = (SS_i - 2 S_i^2/N + C_i S_i^2/N^2)/N,  sum_i SS_i = SS,
//   N = 4194304. One fused pass over x (50.3 MB fp32) + y (16.8 MB int32).
// Two kernels (kernel boundary = the only proven cross-XCD sync; R3's fused
// threadfence variant raced). R8 change: 5 blocks/CU (20 waves/CU) via
// __launch_bounds__(256,5) + 1280 blocks for better memory-latency hiding.

constexpr int kHW = 512 * 512;            // 262144
constexpr int kB = 16;
constexpr int kNPix = kB * kHW;           // 4194304 = N
constexpr int kNCls = 11;
constexpr int kNQ = 2 * kNCls + 1;        // q: 0..10 = S_i, 11..21 = C_i, 22 = SS
constexpr int kBlocks = 1280;             // 5 blocks/CU -> 20 waves/CU
constexpr int kThreads = 256;

__global__ __launch_bounds__(kThreads, 5) void seg_main_kernel(
    const float* __restrict__ x, const int* __restrict__ y,
    double* __restrict__ pd) {
  const int tid = threadIdx.x, bid = blockIdx.x;

  float s[kNCls];
#pragma unroll
  for (int i = 0; i < kNCls; ++i) s[i] = 0.f;
  float ss = 0.f;
  // 11 per-class counts in 5-bit fields at bit 5*cls; m==0 pixels go to
  // cls=12 (bits 60..63, harmless garbage). <=16 px/thread -> no field ovfl.
  unsigned long long pack = 0ull;

  constexpr int kNG = kNPix / 4;                // 1048576 groups
  const int stride = kBlocks * kThreads;        // 327680
  for (int g = bid * kThreads + tid; g < kNG; g += stride) {
    const int p = g << 2;
    const int b = p >> 18;                // p / kHW  (kHW = 2^18)
    const int off = p & (kHW - 1);
    const float* xb = x + (size_t)b * 3 * kHW + off;
    const float4 x0 = *reinterpret_cast<const float4*>(xb);
    const float4 x1 = *reinterpret_cast<const float4*>(xb + kHW);
    const float4 x2 = *reinterpret_cast<const float4*>(xb + 2 * kHW);
    const int4 yv = *reinterpret_cast<const int4*>(y + p);

    const float xm[4] = {(x0.x + x1.x + x2.x) * (1.f / 3.f),
                         (x0.y + x1.y + x2.y) * (1.f / 3.f),
                         (x0.z + x1.z + x2.z) * (1.f / 3.f),
                         (x0.w + x1.w + x2.w) * (1.f / 3.f)};
    const int yy[4] = {yv.x, yv.y, yv.z, yv.w};
#pragma unroll
    for (int j = 0; j < 4; ++j) {
      const float m = xm[j];
      const bool nz = (m != 0.0f);        // exact a2==0 semantics of the ref
      const float mq = nz ? m : 0.f;
      ss = fmaf(mq, m, ss);               // m^2 iff nz
      const int cls = nz ? yy[j] : 12;    // fold nz into the class id once
      pack += 1ull << (5 * cls);          // all 11 counts in one add
#pragma unroll
      for (int i = 0; i < kNCls; ++i)
        s[i] += (cls == i) ? m : 0.f;     // cmp + cndmask + add
    }
  }

  // ---- block epilogue: LDS transpose, 8 lanes per quantity ----
  float qv[kNQ];
#pragma unroll
  for (int i = 0; i < kNCls; ++i) qv[i] = s[i];
#pragma unroll
  for (int i = 0; i < kNCls; ++i)
    qv[kNCls + i] = (float)((unsigned)(pack >> (5 * i)) & 31u);
  qv[2 * kNCls] = ss;

  __shared__ float arr[kNQ][kThreads];
#pragma unroll
  for (int q = 0; q < kNQ; ++q) arr[q][tid] = qv[q];
  __syncthreads();

  if (tid < kNQ * 8) {
    const int q = tid >> 3, l = tid & 7;  // 8 lanes per quantity
    const float4* row = reinterpret_cast<const float4*>(arr[q]);
    double dv = 0.0;
#pragma unroll
    for (int jj = 0; jj < kThreads / 32; ++jj) {  // 8 x float4 per lane
      const float4 v = row[l + 8 * jj];
      dv += (double)((v.x + v.y) + (v.z + v.w));
    }
#pragma unroll
    for (int o = 4; o > 0; o >>= 1) dv += __shfl_down(dv, o, 8);
    if (l == 0) pd[(size_t)q * kBlocks + bid] = dv;  // quantity-major
  }
}

__global__ __launch_bounds__(1024) void seg_final_kernel(
    const double* __restrict__ pd, float* __restrict__ out) {
  __shared__ double tot[kNQ];
  const int q = threadIdx.x >> 5;         // 32 lanes per quantity
  const int lane = threadIdx.x & 31;
  if (q < kNQ) {
    double v = 0.0;
#pragma unroll
    for (int j = 0; j < kBlocks / 32; ++j)   // 40 unrolled independent loads
      v += pd[(size_t)q * kBlocks + lane + 32 * j];
#pragma unroll
    for (int o = 16; o > 0; o >>= 1) v += __shfl_down(v, o, 32);
    if (lane == 0) tot[q] = v;
  }
  __syncthreads();
  if (threadIdx.x == 0) {
    const double N = (double)kNPix;
    double acc = tot[2 * kNCls];          // SS_total
    for (int i = 0; i < kNCls; ++i) {
      const double S = tot[i];
      const double C = tot[kNCls + i];
      acc += S * S * (C / N - 2.0) / N;   // -2 S^2/N + C S^2/N^2
    }
    out[0] = (float)(acc / N);
  }
}

extern "C" void kernel_launch(void* const* d_in, const int* in_sizes, int n_in,
                              void* d_out, int out_size, void* d_ws, size_t ws_size,
                              hipStream_t stream) {
  const float* x = (const float*)d_in[0];
  const int* y = (const int*)d_in[1];
  float* out = (float*)d_out;
  double* pd = (double*)d_ws;             // 23 * 1280 * 8 = 235 KB

  seg_main_kernel<<<kBlocks, kThreads, 0, stream>>>(x, y, pd);
  seg_final_kernel<<<1, 1024, 0, stream>>>(pd, out);
}